// Round 6
// baseline (121.990 us; speedup 1.0000x reference)
//
#include <hip/hip_runtime.h>

#define B_DIM 32
#define C_DIM 64
#define D_DIM 64
#define T_DIM 30000
#define T4    7500
#define JT    128                  // j columns per tile
#define TILES 235                  // ceil(30000/128); last tile has 48 valid cols
#define WORK  (B_DIM * TILES)      // 7520 items
#define WPX   (WORK / 8)           // 940 items per XCD (= exactly 4 batches)
#define GRID  1024                 // 4 blocks per CU exactly
#define BPX   (GRID / 8)           // 128 blocks per XCD

typedef short bf16x8 __attribute__((ext_vector_type(8)));
typedef float f32x16 __attribute__((ext_vector_type(16)));
typedef float f32x4  __attribute__((ext_vector_type(4)));
typedef unsigned short u16x8 __attribute__((ext_vector_type(8)));

__device__ __forceinline__ unsigned short f32_to_bf16_rne(float f) {
    unsigned int u = __builtin_bit_cast(unsigned int, f);
    return (unsigned short)((u + 0x7fffu + ((u >> 16) & 1u)) >> 16);
}

// ---------------- Kernel A: desc[b,c] = mean over T ----------------
__global__ __launch_bounds__(256) void mean_kernel(const float* __restrict__ x,
                                                   float* __restrict__ desc) {
    int r = blockIdx.x;  // b*64 + c
    const float4* xr = (const float4*)(x + (size_t)r * T_DIM);
    float4 s = {0.f, 0.f, 0.f, 0.f};
    for (int i = threadIdx.x; i < T4; i += 256) {
        float4 v = xr[i];
        s.x += v.x; s.y += v.y; s.z += v.z; s.w += v.w;
    }
    float p = (s.x + s.y) + (s.z + s.w);
    #pragma unroll
    for (int off = 32; off > 0; off >>= 1) p += __shfl_down(p, off, 64);
    __shared__ float wsum[4];
    int wave = threadIdx.x >> 6;
    int lane = threadIdx.x & 63;
    if (lane == 0) wsum[wave] = p;
    __syncthreads();
    if (threadIdx.x == 0) {
        float tot = (wsum[0] + wsum[1]) + (wsum[2] + wsum[3]);
        desc[r] = tot * (1.0f / (float)T_DIM);
    }
}

// ---------------- Kernel B: attn2 = bf16(alpha * softmax(logits) + I) ----------------
__global__ __launch_bounds__(64) void attn_kernel(const float* __restrict__ desc,
                                                  const float* __restrict__ Wq,
                                                  const float* __restrict__ bq,
                                                  const float* __restrict__ Wk,
                                                  const float* __restrict__ bk,
                                                  const float* __restrict__ alphap,
                                                  unsigned short* __restrict__ attnb) {
    int b = blockIdx.x;
    int c = threadIdx.x;
    __shared__ float sd[C_DIM];
    sd[c] = desc[b * C_DIM + c];
    __syncthreads();

    float dA = 0.f, dBq = 0.f, dBk = 0.f, dCc = 0.f;
    #pragma unroll
    for (int d = 0; d < D_DIM; ++d) {
        float wq = Wq[d], wk = Wk[d], vq = bq[d], vk = bk[d];
        dA  += wq * wk;
        dBq += wq * vk;
        dBk += vq * wk;
        dCc += vq * vk;
    }

    float dc = sd[c];
    float l[C_DIM];
    float lmax = -1e30f;
    #pragma unroll
    for (int e = 0; e < C_DIM; ++e) {
        float de = sd[e];
        float v = (dA * dc * de + dBq * dc + dBk * de + dCc) * 0.125f;
        l[e] = v;
        lmax = fmaxf(lmax, v);
    }
    float sum = 0.f;
    #pragma unroll
    for (int e = 0; e < C_DIM; ++e) {
        float ev = __expf(l[e] - lmax);
        l[e] = ev;
        sum += ev;
    }
    float inv = alphap[0] / sum;   // fold alpha
    unsigned short* arow = attnb + ((size_t)b * C_DIM + c) * C_DIM;
    #pragma unroll
    for (int e = 0; e < C_DIM; ++e) {
        float v = l[e] * inv + (e == c ? 1.0f : 0.0f);  // fold residual
        arow[e] = f32_to_bf16_rne(v);
    }
}

// ---------------- Kernel C: persistent pipelined MFMA mix ----------------
// 1024 blocks (4/CU). Block handles 7-8 consecutive (b,tile) items, XCD-chunked
// (each XCD owns exactly 4 batches). Double-buffered bf16 x-tiles in LDS
// (2 x 16KB); loads for item i+1 issued one full tile early (async-split);
// out-bounce aliases the just-consumed buffer -> LDS total 32KB.
__global__ __launch_bounds__(256, 4) void mix2(const float* __restrict__ x,
                                               const unsigned short* __restrict__ attnb,
                                               float* __restrict__ out) {
    __shared__ unsigned short xbuf[2][C_DIM][JT];   // 2 x 16 KB

    int g   = blockIdx.x;
    int xcd = g & 7;
    int idx = g >> 3;
    int start = xcd * WPX + ((idx * WPX) >> 7);        // idx*940/128
    int end   = xcd * WPX + (((idx + 1) * WPX) >> 7);

    int t    = threadIdx.x;
    int w    = t >> 6;
    int l31  = t & 31;
    int lhi  = (t >> 5) & 1;
    int jc   = w * 32 + l31;     // compute-phase j col within tile
    int srow = t >> 4;           // staging row base (0..15)
    int c16  = t & 15;           // staging col16

    f32x4 R[4][2];               // in-flight next-tile data (32 VGPR)

    auto issueLoads = [&](int item) {
        int b    = item / TILES;
        int tile = item - b * TILES;
        const float* xb = x + (size_t)b * C_DIM * T_DIM;
        int j0 = tile * JT + c16 * 8;
        if (j0 > T_DIM - 8) j0 = T_DIM - 8;
        #pragma unroll
        for (int p = 0; p < 4; ++p) {
            const float* src = xb + (size_t)(srow + 16 * p) * T_DIM + j0;
            R[p][0] = *(const f32x4*)(src);
            R[p][1] = *(const f32x4*)(src + 4);
        }
    };
    auto writeStage = [&](int buf) {
        #pragma unroll
        for (int p = 0; p < 4; ++p) {
            u16x8 v;
            #pragma unroll
            for (int q = 0; q < 4; ++q) v[q]     = f32_to_bf16_rne(R[p][0][q]);
            #pragma unroll
            for (int q = 0; q < 4; ++q) v[4 + q] = f32_to_bf16_rne(R[p][1][q]);
            *(u16x8*)&xbuf[buf][srow + 16 * p][c16 * 8] = v;
        }
    };

    bf16x8 afrag[2][4];
    int bprev = -1;
    int cur = 0;

    // prologue: fill buffer 0 with item 'start', issue loads for start+1
    issueLoads(start);
    writeStage(0);
    issueLoads(start + 1 < end ? start + 1 : start);
    __syncthreads();

    for (int item = start; item < end; ++item) {
        int b    = item / TILES;
        int tile = item - b * TILES;

        if (b != bprev) {   // rare: ~3 of 128 blocks per XCD cross a b-boundary
            const unsigned short* ab = attnb + (size_t)b * C_DIM * C_DIM;
            #pragma unroll
            for (int m = 0; m < 2; ++m)
                #pragma unroll
                for (int gg = 0; gg < 4; ++gg)
                    afrag[m][gg] = *(const bf16x8*)(ab + (32 * m + l31) * C_DIM + 16 * gg + 8 * lhi);
            bprev = b;
        }

        // ---- compute from xbuf[cur]
        f32x16 acc0 = {}, acc1 = {};
        #pragma unroll
        for (int gg = 0; gg < 4; ++gg) {
            int e0 = 16 * gg + 8 * lhi;
            bf16x8 bfrag;
            #pragma unroll
            for (int i = 0; i < 8; ++i)
                bfrag[i] = (short)xbuf[cur][e0 + i][jc];
            acc0 = __builtin_amdgcn_mfma_f32_32x32x16_bf16(afrag[0][gg], bfrag, acc0, 0, 0, 0);
            acc1 = __builtin_amdgcn_mfma_f32_32x32x16_bf16(afrag[1][gg], bfrag, acc1, 0, 0, 0);
        }

        // ---- stage item+1 into the other buffer (loads issued one tile ago),
        //      then fire loads for item+2
        if (item + 1 < end) {
            writeStage(cur ^ 1);
            issueLoads(item + 2 < end ? item + 2 : end - 1);
        }
        __syncthreads();   // xbuf[cur^1] visible; compute reads of xbuf[cur] done

        // ---- epilogue: bounce acc through o = alias of consumed xbuf[cur]
        float (*o)[JT] = (float (*)[JT]) &xbuf[cur][0][0];   // f32 [32][128] = 16 KB
        float* ob = out + (size_t)b * C_DIM * T_DIM;
        #pragma unroll
        for (int h = 0; h < 2; ++h) {
            #pragma unroll
            for (int r = 0; r < 16; ++r) {
                int crow = (r & 3) + 8 * (r >> 2) + 4 * lhi;
                o[crow][jc] = h ? acc1[r] : acc0[r];
            }
            __syncthreads();
            #pragma unroll
            for (int p = 0; p < 4; ++p) {
                int row  = (t >> 5) + 8 * p;
                f32x4 v  = *(const f32x4*)&o[row][(t & 31) * 4];
                int gcol = tile * JT + (t & 31) * 4;
                if (gcol + 3 < T_DIM)
                    __builtin_nontemporal_store(
                        v, (f32x4*)(ob + (size_t)(h * 32 + row) * T_DIM + gcol));
            }
            __syncthreads();
        }
        cur ^= 1;
    }
}

extern "C" void kernel_launch(void* const* d_in, const int* in_sizes, int n_in,
                              void* d_out, int out_size, void* d_ws, size_t ws_size,
                              hipStream_t stream) {
    const float* x     = (const float*)d_in[0];
    const float* Wq    = (const float*)d_in[1];
    const float* bq    = (const float*)d_in[2];
    const float* Wk    = (const float*)d_in[3];
    const float* bk    = (const float*)d_in[4];
    // d_in[5] = Wv, d_in[6] = bv: dead code in the reference
    const float* alpha = (const float*)d_in[7];
    float* out = (float*)d_out;

    float* desc = (float*)d_ws;                                       // 8 KB
    unsigned short* attnb = (unsigned short*)(desc + B_DIM * C_DIM);  // 256 KB bf16

    mean_kernel<<<B_DIM * C_DIM, 256, 0, stream>>>(x, desc);
    attn_kernel<<<B_DIM, 64, 0, stream>>>(desc, Wq, bq, Wk, bk, alpha, attnb);
    mix2<<<GRID, 256, 0, stream>>>(x, attnb, out);
}